// Round 11
// baseline (701.029 us; speedup 1.0000x reference)
//
#include <hip/hip_runtime.h>
#include <hip/hip_bf16.h>
#include <stdint.h>

#define NVOX 131072
#define CCH  128
#define EPSV 1e-4f

typedef __bf16 bf16_t;
typedef bf16_t bf16x8 __attribute__((ext_vector_type(8)));
typedef bf16_t bf16x4 __attribute__((ext_vector_type(4)));
typedef float  f32x4  __attribute__((ext_vector_type(4)));

__device__ __forceinline__ void async16(void* lds, const void* g) {
    __builtin_amdgcn_global_load_lds(
        (const __attribute__((address_space(1))) uint32_t*)g,
        (__attribute__((address_space(3))) uint32_t*)lds, 16, 0, 0);
}

// ---------- prep: features f32 -> bf16 ----------
__global__ void k_prep_feat(const float* __restrict__ f, bf16_t* __restrict__ fb) {
    int i = blockIdx.x * 256 + threadIdx.x;      // over N*C/4 = 4194304 exactly
    const float4* f4 = (const float4*)f;
    float4 v = f4[i];
    bf16x4 o;
    o[0] = (bf16_t)v.x; o[1] = (bf16_t)v.y; o[2] = (bf16_t)v.z; o[3] = (bf16_t)v.w;
    ((bf16x4*)fb)[i] = o;
}

// ---------- prep: W [27,Ci,Co] f32 -> W^T [k][co][ci] bf16 (3 layers);
// ---------- block 81 also zeroes pad rows + stats ----------
__global__ void k_prep_w(const float* __restrict__ w0, const float* __restrict__ w1,
                         const float* __restrict__ w2, bf16_t* __restrict__ wbt,
                         bf16_t* featb, bf16_t* xb1, bf16_t* xb2, float* stats) {
    int blk = blockIdx.x;                // 0..81
    if (blk == 81) {
        int t = threadIdx.x;
        if (t < 128) {
            featb[(size_t)NVOX * CCH + t] = (bf16_t)0.0f;
            xb1[(size_t)NVOX * CCH + t]   = (bf16_t)0.0f;
            xb2[(size_t)NVOX * CCH + t]   = (bf16_t)0.0f;
        }
        for (int i = t; i < 768; i += 256) stats[i] = 0.0f;
        return;
    }
    int layer = blk / 27, k = blk % 27;
    const float* w = (layer == 0 ? w0 : (layer == 1 ? w1 : w2)) + k * 16384;
    __shared__ bf16_t tile[128][132];
    for (int e = threadIdx.x; e < 16384; e += 256) {
        int ci = e >> 7, co = e & 127;
        tile[co][ci] = (bf16_t)w[e];
    }
    __syncthreads();
    bf16_t* out = wbt + (size_t)blk * 16384;
    for (int e = threadIdx.x; e < 16384; e += 256) {
        int co = e >> 7, ci = e & 127;
        out[e] = tile[co][ci];
    }
}

// ---------- conv: gather-GEMM 64x128 tile, bf16 MFMA, + channel stats ----------
// r10's chunk structure VERBATIM (two __syncthreads, single-buffer, T2
// swizzle, compiler-scheduled) with ONE change: tile 128x128 -> 64x128
// (M-split, 2048 blocks). acc halves to 32 regs, LDS drops to 20.2KB ->
// target 5 blocks/CU (20 waves, 5 independent barrier groups) vs the 12-wave
// cap that r8/r10 hit. A-gather traffic unchanged (rows partition); B L2
// re-reads double (still under L2 ceiling). Swizzle formulas unchanged
// (all row bases are multiples of 4, so (row>>1)&3 depends only on lrow).
__global__ __launch_bounds__(256, 4) void k_conv(
        const bf16_t* __restrict__ featb,   // (N+1) x 128 bf16
        const bf16_t* __restrict__ wbt,     // 27 x 128co x 128ci bf16
        const int* __restrict__ nbr,        // N x 27 int32
        bf16_t* __restrict__ out,           // N x 128 bf16
        float* __restrict__ stat)           // [0..127]=sum, [128..255]=sumsq
{
    __shared__ uint32_t offs[27 * 64];      // 6912 B
    __shared__ bf16_t smA[64 * 32];         // 4096 B: 64 rows x 64 B
    __shared__ bf16_t smB[128 * 32];        // 8192 B: 128 rows x 64 B
    __shared__ float ssum[128], ssq[128];   // 1024 B  (total 20224 B)

    const int tid = threadIdx.x;
    const int m0 = blockIdx.x << 6;          // 64 rows per block

    if (tid < 128) { ssum[tid] = 0.0f; ssq[tid] = 0.0f; }

    for (int e = tid; e < 27 * 64; e += 256) {
        int row = e / 27, k = e - row * 27;
        int idx = nbr[(size_t)(m0 + row) * 27 + k];
        offs[(k << 6) + row] = ((uint32_t)(idx < 0 ? NVOX : idx)) << 8;  // byte offset
    }
    __syncthreads();

    const int l = tid & 63, w = tid >> 6;    // 4 waves
    const int wm = w >> 1, wn = w & 1;       // 2M x 2N, wave owns 32x64
    const int lrow = l & 15, lq = l >> 4;

    const int arow = tid >> 2;               // staging row 0..63 (A and B-low)
    // source-side swizzle: slot (tid&3) of row arow holds chunk
    // (tid&3)^((arow>>1)&3); arow>>1 == tid>>3. Same involution for B rows
    // arow and arow+64 (+64 doesn't change (row>>1)&3).
    const int ssub = (((tid & 3) ^ ((tid >> 3) & 3)) << 4);
    // read-side swizzle: chunk lq of row R lives at slot lq ^ ((R>>1)&3)
    const int cxor = ((lq ^ ((lrow >> 1) & 3)) << 4);

    char* dstA  = (char*)smA + (w << 10);    // wave rows 16w..16w+15
    char* dstB0 = (char*)smB + (w << 10);
    char* dstB1 = (char*)smB + 4096 + (w << 10);

    const char* fbase = (const char*)featb;
    const char* wbase = (const char*)wbt;

    f32x4 acc[2][4] = {};

    for (int k = 0; k < 27; ++k) {
        uint32_t offA = offs[(k << 6) + arow];
        const char* wk = wbase + ((size_t)k << 15);   // k * 128*128*2
        #pragma unroll
        for (int c = 0; c < 4; ++c) {
            const int cb = c << 6;                    // ci-chunk byte offset
            __syncthreads();
            async16(dstA,  fbase + offA + cb + ssub);
            async16(dstB0, wk + (arow << 8) + cb + ssub);
            async16(dstB1, wk + ((arow + 64) << 8) + cb + ssub);
            __syncthreads();

            bf16x8 af[2], bfr[4];
            #pragma unroll
            for (int i = 0; i < 2; ++i)
                af[i]  = *(const bf16x8*)((const char*)smA +
                          (((wm << 5) + (i << 4) + lrow) << 6) + cxor);
            #pragma unroll
            for (int j = 0; j < 4; ++j)
                bfr[j] = *(const bf16x8*)((const char*)smB +
                          (((wn << 6) + (j << 4) + lrow) << 6) + cxor);
            #pragma unroll
            for (int i = 0; i < 2; ++i)
                #pragma unroll
                for (int j = 0; j < 4; ++j)
                    acc[i][j] = __builtin_amdgcn_mfma_f32_16x16x32_bf16(
                        af[i], bfr[j], acc[i][j], 0, 0, 0);
        }
    }

    // epilogue: store (bf16) + per-channel stats (f32 from acc)
    float csum[4] = {0, 0, 0, 0}, csq[4] = {0, 0, 0, 0};
    #pragma unroll
    for (int j = 0; j < 4; ++j) {
        int col = (wn << 6) + (j << 4) + lrow;
        #pragma unroll
        for (int i = 0; i < 2; ++i) {
            int grow = m0 + (wm << 5) + (i << 4) + (lq << 2);
            #pragma unroll
            for (int r = 0; r < 4; ++r) {
                float v = acc[i][j][r];
                out[(size_t)(grow + r) * CCH + col] = (bf16_t)v;
                csum[j] += v;
                csq[j]  += v * v;
            }
        }
    }
    #pragma unroll
    for (int j = 0; j < 4; ++j) {
        csum[j] += __shfl_xor(csum[j], 16, 64);
        csum[j] += __shfl_xor(csum[j], 32, 64);
        csq[j]  += __shfl_xor(csq[j], 16, 64);
        csq[j]  += __shfl_xor(csq[j], 32, 64);
    }
    if (lq == 0) {
        #pragma unroll
        for (int j = 0; j < 4; ++j) {
            int col = (wn << 6) + (j << 4) + lrow;
            atomicAdd(&ssum[col], csum[j]);
            atomicAdd(&ssq[col],  csq[j]);
        }
    }
    __syncthreads();
    if (tid < 128) {
        atomicAdd(&stat[tid],       ssum[tid]);
        atomicAdd(&stat[128 + tid], ssq[tid]);
    }
}

// ---------- BN + LeakyReLU (bf16 in) -> bf16 next-layer input ----------
__global__ void k_bnact(const bf16_t* __restrict__ x, const float* __restrict__ stat,
                        const float* __restrict__ g, const float* __restrict__ b,
                        bf16_t* __restrict__ out, float slope) {
    __shared__ float sc[128], sh[128];
    int tid = threadIdx.x;
    if (tid < 128) {
        float mu  = stat[tid] * (1.0f / NVOX);
        float var = stat[128 + tid] * (1.0f / NVOX) - mu * mu;
        float inv = rsqrtf(var + EPSV);
        float s = g[tid] * inv;
        sc[tid] = s;
        sh[tid] = b[tid] - mu * s;
    }
    __syncthreads();
    int i = blockIdx.x * 256 + tid;              // over N*C/8 = 2097152
    bf16x8 v = ((const bf16x8*)x)[i];
    int c = (i << 3) & 127;
    bf16x8 o;
    #pragma unroll
    for (int e = 0; e < 8; ++e) {
        float y = (float)v[e] * sc[c + e] + sh[c + e];
        y = y >= 0.0f ? y : slope * y;
        o[e] = (bf16_t)y;
    }
    ((bf16x8*)out)[i] = o;
}

// ---------- BN3 + residual + LeakyReLU(1/3) -> f32 d_out ----------
__global__ void k_final(const bf16_t* __restrict__ x, const float* __restrict__ stat,
                        const float* __restrict__ g, const float* __restrict__ b,
                        const bf16_t* __restrict__ res, float* __restrict__ out) {
    __shared__ float sc[128], sh[128];
    int tid = threadIdx.x;
    if (tid < 128) {
        float mu  = stat[tid] * (1.0f / NVOX);
        float var = stat[128 + tid] * (1.0f / NVOX) - mu * mu;
        float inv = rsqrtf(var + EPSV);
        float s = g[tid] * inv;
        sc[tid] = s;
        sh[tid] = b[tid] - mu * s;
    }
    __syncthreads();
    int i = blockIdx.x * 256 + tid;              // over N*C/8
    bf16x8 v = ((const bf16x8*)x)[i];
    bf16x8 r = ((const bf16x8*)res)[i];
    int c = (i << 3) & 127;
    const float k3 = 1.0f / 3.0f;
    float yy[8];
    #pragma unroll
    for (int e = 0; e < 8; ++e) {
        float y = (float)v[e] * sc[c + e] + sh[c + e] + (float)r[e];
        yy[e] = y >= 0.0f ? y : k3 * y;
    }
    float4 o0, o1;
    o0.x = yy[0]; o0.y = yy[1]; o0.z = yy[2]; o0.w = yy[3];
    o1.x = yy[4]; o1.y = yy[5]; o1.z = yy[6]; o1.w = yy[7];
    ((float4*)out)[2 * i]     = o0;
    ((float4*)out)[2 * i + 1] = o1;
}

extern "C" void kernel_launch(void* const* d_in, const int* in_sizes, int n_in,
                              void* d_out, int out_size, void* d_ws, size_t ws_size,
                              hipStream_t stream) {
    (void)in_sizes; (void)n_in; (void)out_size; (void)ws_size;
    const float* features = (const float*)d_in[0];
    const int*   nbr      = (const int*)d_in[1];
    const float* w1 = (const float*)d_in[2];
    const float* w2 = (const float*)d_in[3];
    const float* w3 = (const float*)d_in[4];
    const float* g1 = (const float*)d_in[5];
    const float* b1 = (const float*)d_in[6];
    const float* g2 = (const float*)d_in[7];
    const float* b2 = (const float*)d_in[8];
    const float* g3 = (const float*)d_in[9];
    const float* b3 = (const float*)d_in[10];

    char* ws = (char*)d_ws;
    const size_t SZ_FB = (size_t)(NVOX + 1) * CCH * 2;   // bf16 buffer w/ zero row
    bf16_t* featb    = (bf16_t*)(ws);
    bf16_t* xb1      = (bf16_t*)(ws + SZ_FB);
    bf16_t* xb2      = (bf16_t*)(ws + 2 * SZ_FB);
    bf16_t* conv_out = (bf16_t*)(ws + 3 * SZ_FB);
    bf16_t* wbt      = (bf16_t*)(ws + 3 * SZ_FB + (size_t)NVOX * CCH * 2);
    float*  stats    = (float*)(ws + 3 * SZ_FB + (size_t)NVOX * CCH * 2
                                + (size_t)3 * 27 * 128 * 128 * 2);

    k_prep_feat<<<16384, 256, 0, stream>>>(features, featb);
    k_prep_w<<<82, 256, 0, stream>>>(w1, w2, w3, wbt, featb, xb1, xb2, stats);

    k_conv<<<2048, 256, 0, stream>>>(featb, wbt, nbr, conv_out, stats);
    k_bnact<<<8192, 256, 0, stream>>>(conv_out, stats, g1, b1, xb1, 0.05f);

    k_conv<<<2048, 256, 0, stream>>>(xb1, wbt + (size_t)27 * 16384, nbr, conv_out, stats + 256);
    k_bnact<<<8192, 256, 0, stream>>>(conv_out, stats + 256, g2, b2, xb2, 0.05f);

    k_conv<<<2048, 256, 0, stream>>>(xb2, wbt + (size_t)2 * 27 * 16384, nbr, conv_out, stats + 512);
    k_final<<<8192, 256, 0, stream>>>(conv_out, stats + 512, g3, b3, xb1, (float*)d_out);
}